// Round 1
// baseline (291.125 us; speedup 1.0000x reference)
//
#include <hip/hip_runtime.h>
#include <hip/hip_bf16.h>

#define TT 28
#define II 28
#define HH 64
#define OO 10
#define EPB 32   // batch elements per block
#define TPE 8    // threads per element (j-slices)
#define JPT 8    // hidden rows per thread
#define BLOCK 256

__global__ __launch_bounds__(BLOCK) void rnn_fwd(
    const float* __restrict__ X, const float* __restrict__ W_ih,
    const float* __restrict__ W_hh, const float* __restrict__ b_ih,
    const float* __restrict__ b_hh, const float* __restrict__ W_out,
    const float* __restrict__ b_out, float* __restrict__ out)
{
    __shared__ float sWih[II][HH];      // transposed: sWih[i][j] = W_ih[j][i]
    __shared__ float sWhh[HH][HH];      // transposed: sWhh[k][j] = W_hh[j][k]
    __shared__ float sWout[OO][HH + 1]; // [o][k], pad +1 to break bank aliasing
    __shared__ float sBias[HH];
    __shared__ float sBo[OO];
    __shared__ float hbuf[2][EPB][HH + 4]; // pad 4 floats: 16B-aligned rows, conflict-free f4 reads

    const int tid = threadIdx.x;

    // ---- stage weights (one-time) ----
    for (int idx = tid; idx < HH * II; idx += BLOCK) {
        int j = idx / II, i = idx - j * II;
        sWih[i][j] = W_ih[idx];
    }
    for (int idx = tid; idx < HH * HH; idx += BLOCK) {
        int j = idx >> 6, k = idx & 63;
        sWhh[k][j] = W_hh[idx];
    }
    for (int idx = tid; idx < OO * HH; idx += BLOCK) {
        int o = idx >> 6, k = idx & 63;
        sWout[o][k] = W_out[idx];
    }
    if (tid < HH) sBias[tid] = b_ih[tid] + b_hh[tid];
    if (tid < OO) sBo[tid] = b_out[tid];

    const int e    = tid >> 3;  // 0..31: element within block
    const int sub  = tid & 7;   // 0..7 : j-slice
    const int gelem = blockIdx.x * EPB + e;
    const float* xrow = X + (size_t)gelem * (TT * II);

    // h0 = 0
    #pragma unroll
    for (int jj = 0; jj < JPT; ++jj) hbuf[0][e][sub * JPT + jj] = 0.f;
    __syncthreads();

    int cur = 0;
    for (int t = 0; t < TT; ++t) {
        // ---- load x_t (7 x float4, 16B-aligned: 784*4 and 112 both %16==0) ----
        float x[II];
        const float4* xp4 = reinterpret_cast<const float4*>(xrow + t * II);
        #pragma unroll
        for (int q = 0; q < 7; ++q) {
            float4 v = xp4[q];
            x[4 * q + 0] = v.x; x[4 * q + 1] = v.y;
            x[4 * q + 2] = v.z; x[4 * q + 3] = v.w;
        }

        float acc[JPT];
        #pragma unroll
        for (int jj = 0; jj < JPT; ++jj) acc[jj] = sBias[sub * JPT + jj];

        // ---- input projection: acc[jj] += W_ih[j][i] * x[i] ----
        #pragma unroll
        for (int i = 0; i < II; ++i) {
            const float4* wr = reinterpret_cast<const float4*>(&sWih[i][sub * JPT]);
            float4 w0 = wr[0], w1 = wr[1];
            float w[8] = {w0.x, w0.y, w0.z, w0.w, w1.x, w1.y, w1.z, w1.w};
            float xv = x[i];
            #pragma unroll
            for (int jj = 0; jj < 8; ++jj) acc[jj] += w[jj] * xv;
        }

        // ---- recurrent: acc[jj] += W_hh[j][k] * h[k] ----
        #pragma unroll
        for (int k4 = 0; k4 < HH / 4; ++k4) {
            float4 h4 = *reinterpret_cast<const float4*>(&hbuf[cur][e][k4 * 4]);
            float hv[4] = {h4.x, h4.y, h4.z, h4.w};
            #pragma unroll
            for (int kk = 0; kk < 4; ++kk) {
                const float4* wr =
                    reinterpret_cast<const float4*>(&sWhh[k4 * 4 + kk][sub * JPT]);
                float4 w0 = wr[0], w1 = wr[1];
                float w[8] = {w0.x, w0.y, w0.z, w0.w, w1.x, w1.y, w1.z, w1.w};
                #pragma unroll
                for (int jj = 0; jj < 8; ++jj) acc[jj] += w[jj] * hv[kk];
            }
        }

        // ---- tanh + write h_new ----
        #pragma unroll
        for (int jj = 0; jj < JPT; ++jj) {
            float a = acc[jj];
            float z = __expf(2.f * a);                       // inf/0 saturate correctly
            float th = 1.f - 2.f * __builtin_amdgcn_rcpf(z + 1.f);
            hbuf[cur ^ 1][e][sub * JPT + jj] = th;
        }
        __syncthreads();
        cur ^= 1;
    }

    // ---- output head: out[b][o] = h . W_out[o] + b_out[o] ----
    const float* hrow = &hbuf[cur][e][0];
    for (int o = sub; o < OO; o += TPE) {  // sub covers o; sub 0,1 also cover 8,9
        float acc = sBo[o];
        #pragma unroll
        for (int k = 0; k < HH; ++k) acc += sWout[o][k] * hrow[k];
        out[(size_t)gelem * OO + o] = acc;
    }
}

extern "C" void kernel_launch(void* const* d_in, const int* in_sizes, int n_in,
                              void* d_out, int out_size, void* d_ws, size_t ws_size,
                              hipStream_t stream) {
    const float* X     = (const float*)d_in[0];
    const float* W_ih  = (const float*)d_in[1];
    const float* W_hh  = (const float*)d_in[2];
    const float* b_ih  = (const float*)d_in[3];
    const float* b_hh  = (const float*)d_in[4];
    const float* W_out = (const float*)d_in[5];
    const float* b_out = (const float*)d_in[6];
    float* out = (float*)d_out;

    const int B = in_sizes[0] / (TT * II);   // 32768
    dim3 grid(B / EPB), block(BLOCK);
    hipLaunchKernelGGL(rnn_fwd, grid, block, 0, stream,
                       X, W_ih, W_hh, b_ih, b_hh, W_out, b_out, out);
}

// Round 2
// 64.532 us; speedup vs baseline: 4.5113x; 4.5113x over previous
//
#include <hip/hip_runtime.h>

#define TT 28
#define II 28
#define HH 64
#define OO 10

typedef __attribute__((ext_vector_type(8))) __bf16 bf16x8;
typedef __attribute__((ext_vector_type(4))) float f32x4;

union FragU { unsigned u[4]; bf16x8 v; };

__device__ __forceinline__ unsigned short f2bf(float f) {
    unsigned u = __builtin_bit_cast(unsigned, f);
    return (unsigned short)((u + 0x7FFFu + ((u >> 16) & 1u)) >> 16);
}
__device__ __forceinline__ float bf2f(unsigned short s) {
    return __builtin_bit_cast(float, (unsigned)s << 16);
}
__device__ __forceinline__ unsigned pk(float lo, float hi) {
    return (unsigned)f2bf(lo) | ((unsigned)f2bf(hi) << 16);
}

#define MFMA(A, B, C) __builtin_amdgcn_mfma_f32_16x16x32_bf16((A), (B), (C), 0, 0, 0)

// Transposed-recurrence MFMA RNN.
// D[j,b] = sum_k W[j,k] * h[b,k]; A-frag = W (row=lane&15, k=8*(lane>>4)+0..7),
// B-frag = h (col=lane&15=b, same k grouping), C/D: col=lane&15=b, row=4*(lane>>4)+reg.
// Each wave owns 16 batch elements across all 28 steps; no LDS, no barriers.
__global__ __launch_bounds__(256, 2) void rnn_mfma(
    const float* __restrict__ X, const float* __restrict__ W_ih,
    const float* __restrict__ W_hh, const float* __restrict__ b_ih,
    const float* __restrict__ b_hh, const float* __restrict__ W_out,
    const float* __restrict__ b_out, float* __restrict__ out)
{
    const int lane = threadIdx.x & 63;
    const int wave = threadIdx.x >> 6;
    const int m15  = lane & 15;        // = batch col for B/C, = j row for A
    const int g    = lane >> 4;        // k-group (and C row-group)
    const bool hiHalf = (g >> 1) != 0;
    const int bglob = blockIdx.x * 64 + wave * 16 + m15;

    // ---- W_hh fragments (A), split hi/lo bf16 ----
    FragU whhhi[4][2], whhlo[4][2];
    #pragma unroll
    for (int jt = 0; jt < 4; ++jt) {
        #pragma unroll
        for (int kb = 0; kb < 2; ++kb) {
            const float* p = W_hh + (16 * jt + m15) * HH + 32 * kb + 8 * g;
            float4 a = *(const float4*)p;
            float4 c = *(const float4*)(p + 4);
            float w[8] = {a.x, a.y, a.z, a.w, c.x, c.y, c.z, c.w};
            #pragma unroll
            for (int u = 0; u < 4; ++u) {
                unsigned hw = pk(w[2 * u], w[2 * u + 1]);
                whhhi[jt][kb].u[u] = hw;
                whhlo[jt][kb].u[u] =
                    pk(w[2 * u]     - bf2f((unsigned short)(hw & 0xFFFFu)),
                       w[2 * u + 1] - bf2f((unsigned short)(hw >> 16)));
            }
        }
    }

    // ---- W_ih fragments (A), K padded to 32: k=28 carries bias, 29..31 zero ----
    FragU wihhi[4], wihlo[4];
    #pragma unroll
    for (int jt = 0; jt < 4; ++jt) {
        int j = 16 * jt + m15;
        float wv[8];
        #pragma unroll
        for (int e = 0; e < 8; ++e) {
            int k = 8 * g + e;
            float v = 0.f;
            if (k < II)       v = W_ih[j * II + k];
            else if (k == II) v = b_ih[j] + b_hh[j];
            wv[e] = v;
        }
        #pragma unroll
        for (int u = 0; u < 4; ++u) {
            unsigned hw = pk(wv[2 * u], wv[2 * u + 1]);
            wihhi[jt].u[u] = hw;
            wihlo[jt].u[u] =
                pk(wv[2 * u]     - bf2f((unsigned short)(hw & 0xFFFFu)),
                   wv[2 * u + 1] - bf2f((unsigned short)(hw >> 16)));
        }
    }

    // bpermute byte-indices for the j->k fragment re-layout (constant per lane)
    int idx[4];
    #pragma unroll
    for (int w = 0; w < 4; ++w)
        idx[w] = 4 * (m15 + 16 * (2 * (g & 1) + (w >> 1)));

    const float* xbase = X + (size_t)bglob * (TT * II);

    // prefetch x for t=0
    float4 xr0, xr1;
    {
        const float* p = xbase + 8 * g;
        xr0 = *(const float4*)p;
        xr1 = (g < 3) ? *(const float4*)(p + 4) : make_float4(1.f, 0.f, 0.f, 0.f);
    }

    FragU hhi[2], hlo[2];   // h B-fragments, valid for t>=1
    float th[4][4];

    for (int t = 0; t < TT; ++t) {
        // build x B-fragments (hi/lo split)
        float xv[8] = {xr0.x, xr0.y, xr0.z, xr0.w, xr1.x, xr1.y, xr1.z, xr1.w};
        FragU xhi, xlo;
        #pragma unroll
        for (int u = 0; u < 4; ++u) {
            unsigned hw = pk(xv[2 * u], xv[2 * u + 1]);
            xhi.u[u] = hw;
            xlo.u[u] = pk(xv[2 * u]     - bf2f((unsigned short)(hw & 0xFFFFu)),
                          xv[2 * u + 1] - bf2f((unsigned short)(hw >> 16)));
        }
        // prefetch next t
        if (t < TT - 1) {
            const float* p = xbase + (t + 1) * II + 8 * g;
            xr0 = *(const float4*)p;
            xr1 = (g < 3) ? *(const float4*)(p + 4) : make_float4(1.f, 0.f, 0.f, 0.f);
        }

        // x-projection (+bias via k=28): acc = Wih_hi*x_hi + Wih_hi*x_lo + Wih_lo*x_hi
        f32x4 accv[4];
        #pragma unroll
        for (int jt = 0; jt < 4; ++jt) {
            f32x4 a = {0.f, 0.f, 0.f, 0.f};
            a = MFMA(wihhi[jt].v, xhi.v, a);
            a = MFMA(wihhi[jt].v, xlo.v, a);
            a = MFMA(wihlo[jt].v, xhi.v, a);
            accv[jt] = a;
        }
        // recurrent part
        if (t > 0) {
            #pragma unroll
            for (int jt = 0; jt < 4; ++jt) {
                f32x4 a = accv[jt];
                #pragma unroll
                for (int kb = 0; kb < 2; ++kb) {
                    a = MFMA(whhhi[jt][kb].v, hhi[kb].v, a);
                    a = MFMA(whhhi[jt][kb].v, hlo[kb].v, a);
                    a = MFMA(whhlo[jt][kb].v, hhi[kb].v, a);
                }
                accv[jt] = a;
            }
        }

        // tanh(a) = 1 - 2/(1+exp(2a))
        #pragma unroll
        for (int jt = 0; jt < 4; ++jt) {
            #pragma unroll
            for (int r = 0; r < 4; ++r) {
                float aa = accv[jt][r];
                float e = __expf(2.f * aa);
                th[jt][r] = 1.f - 2.f * __builtin_amdgcn_rcpf(e + 1.f);
            }
        }

        if (t < TT - 1) {
            // pack tanh results (hi/lo) then redistribute j->k via ds_bpermute
            unsigned phi[4][2], plo[4][2];
            #pragma unroll
            for (int jt = 0; jt < 4; ++jt) {
                #pragma unroll
                for (int u = 0; u < 2; ++u) {
                    unsigned hw = pk(th[jt][2 * u], th[jt][2 * u + 1]);
                    phi[jt][u] = hw;
                    plo[jt][u] =
                        pk(th[jt][2 * u]     - bf2f((unsigned short)(hw & 0xFFFFu)),
                           th[jt][2 * u + 1] - bf2f((unsigned short)(hw >> 16)));
                }
            }
            #pragma unroll
            for (int kb = 0; kb < 2; ++kb) {
                #pragma unroll
                for (int w = 0; w < 4; ++w) {
                    int c0 = __builtin_amdgcn_ds_bpermute(idx[w], (int)phi[2 * kb][w & 1]);
                    int c1 = __builtin_amdgcn_ds_bpermute(idx[w], (int)phi[2 * kb + 1][w & 1]);
                    hhi[kb].u[w] = (unsigned)(hiHalf ? c1 : c0);
                    c0 = __builtin_amdgcn_ds_bpermute(idx[w], (int)plo[2 * kb][w & 1]);
                    c1 = __builtin_amdgcn_ds_bpermute(idx[w], (int)plo[2 * kb + 1][w & 1]);
                    hlo[kb].u[w] = (unsigned)(hiHalf ? c1 : c0);
                }
            }
        }
    }

    // ---- output head: out[b,o] = h . W_out[o,:] + b_out[o] ----
    float po[OO];
    #pragma unroll
    for (int o = 0; o < OO; ++o) {
        float s = 0.f;
        #pragma unroll
        for (int jt = 0; jt < 4; ++jt) {
            float4 wv = *(const float4*)(W_out + o * HH + 16 * jt + 4 * g);
            s += th[jt][0] * wv.x + th[jt][1] * wv.y +
                 th[jt][2] * wv.z + th[jt][3] * wv.w;
        }
        s += __shfl_xor(s, 16);
        s += __shfl_xor(s, 32);
        po[o] = s;
    }
    if (g == 0) {
        #pragma unroll
        for (int o = 0; o < OO; ++o)
            out[(size_t)bglob * OO + o] = po[o] + b_out[o];
    }
}

extern "C" void kernel_launch(void* const* d_in, const int* in_sizes, int n_in,
                              void* d_out, int out_size, void* d_ws, size_t ws_size,
                              hipStream_t stream) {
    const float* X     = (const float*)d_in[0];
    const float* W_ih  = (const float*)d_in[1];
    const float* W_hh  = (const float*)d_in[2];
    const float* b_ih  = (const float*)d_in[3];
    const float* b_hh  = (const float*)d_in[4];
    const float* W_out = (const float*)d_in[5];
    const float* b_out = (const float*)d_in[6];
    float* out = (float*)d_out;

    const int B = in_sizes[0] / (TT * II);   // 32768
    dim3 grid(B / 64), block(256);           // 4 waves x 16 batch elems per block
    hipLaunchKernelGGL(rnn_mfma, grid, block, 0, stream,
                       X, W_ih, W_hh, b_ih, b_hh, W_out, b_out, out);
}

// Round 3
// 53.010 us; speedup vs baseline: 5.4919x; 1.2174x over previous
//
#include <hip/hip_runtime.h>

#define TT 28
#define II 28
#define HH 64
#define OO 10

typedef __attribute__((ext_vector_type(8))) __bf16 bf16x8;
typedef __attribute__((ext_vector_type(2))) __bf16 bf16x2;
typedef __attribute__((ext_vector_type(4))) float f32x4;

union FragU { unsigned u[4]; bf16x8 v; };

__device__ __forceinline__ unsigned cvtpk(float f0, float f1) {
    bf16x2 p; p.x = (__bf16)f0; p.y = (__bf16)f1;   // -> v_cvt_pk_bf16_f32
    return __builtin_bit_cast(unsigned, p);
}
// split (f0,f1) into packed bf16 hi + packed bf16 lo (residual)
__device__ __forceinline__ void split2(float f0, float f1, unsigned& hi, unsigned& lo) {
    unsigned hb = cvtpk(f0, f1);
    float h0 = __builtin_bit_cast(float, hb << 16);
    float h1 = __builtin_bit_cast(float, hb & 0xFFFF0000u);
    lo = cvtpk(f0 - h0, f1 - h1);
    hi = hb;
}

#define MFMA(A, B, C) __builtin_amdgcn_mfma_f32_16x16x32_bf16((A), (B), (C), 0, 0, 0)

// Transposed-recurrence MFMA RNN with PERMUTED row layout:
// A-frag tile jt carries W rows j(jt,rho) = 32*(jt>>1) + 8*(rho>>2) + 4*(jt&1) + (rho&3).
// Then lane (g,b) ends the step holding th[jt][r] = h[32*(jt>>1)+8g+4*(jt&1)+r],
// which is EXACTLY its own B-fragment for the next step:
//   Bfrag[kb][e] = th[2kb+(e>>2)][e&3]   (zero cross-lane traffic, zero LDS).
__global__ __launch_bounds__(256, 2) void rnn_mfma2(
    const float* __restrict__ X, const float* __restrict__ W_ih,
    const float* __restrict__ W_hh, const float* __restrict__ b_ih,
    const float* __restrict__ b_hh, const float* __restrict__ W_out,
    const float* __restrict__ b_out, float* __restrict__ out)
{
    const int lane = threadIdx.x & 63;
    const int wave = threadIdx.x >> 6;
    const int m15  = lane & 15;        // batch col for B/C, row-within-tile for A
    const int g    = lane >> 4;        // k-group / C row-group
    const int bglob = blockIdx.x * 64 + wave * 16 + m15;
    const int rowhi = 8 * (m15 >> 2) + (m15 & 3);   // permuted-row component

    // ---- W_hh A-fragments (hi/lo split), permuted rows ----
    FragU whhhi[4][2], whhlo[4][2];
    #pragma unroll
    for (int jt = 0; jt < 4; ++jt) {
        const int jA = 32 * (jt >> 1) + 4 * (jt & 1) + rowhi;
        #pragma unroll
        for (int kb = 0; kb < 2; ++kb) {
            const float* p = W_hh + jA * HH + 32 * kb + 8 * g;
            float4 a = *(const float4*)p;
            float4 c = *(const float4*)(p + 4);
            float w[8] = {a.x, a.y, a.z, a.w, c.x, c.y, c.z, c.w};
            #pragma unroll
            for (int u = 0; u < 4; ++u)
                split2(w[2 * u], w[2 * u + 1],
                       whhhi[jt][kb].u[u], whhlo[jt][kb].u[u]);
        }
    }

    // ---- W_ih A-fragments, K padded to 32 (k=28 carries bias), permuted rows ----
    FragU wihhi[4], wihlo[4];
    #pragma unroll
    for (int jt = 0; jt < 4; ++jt) {
        const int jA = 32 * (jt >> 1) + 4 * (jt & 1) + rowhi;
        float wv[8];
        #pragma unroll
        for (int e = 0; e < 8; ++e) {
            int k = 8 * g + e;
            float v = 0.f;
            if (k < II)       v = W_ih[jA * II + k];
            else if (k == II) v = b_ih[jA] + b_hh[jA];
            wv[e] = v;
        }
        #pragma unroll
        for (int u = 0; u < 4; ++u)
            split2(wv[2 * u], wv[2 * u + 1], wihhi[jt].u[u], wihlo[jt].u[u]);
    }

    const float* xbase = X + (size_t)bglob * (TT * II);

    // prefetch x for t=0 (k=28 is the bias column: x28 = 1)
    float4 xr0, xr1;
    {
        const float* p = xbase + 8 * g;
        xr0 = *(const float4*)p;
        xr1 = (g < 3) ? *(const float4*)(p + 4) : make_float4(1.f, 0.f, 0.f, 0.f);
    }

    FragU hhi[2], hlo[2];   // h B-fragments, valid for t>=1
    float th[4][4];

    for (int t = 0; t < TT; ++t) {
        // ---- build x B-fragments (hi/lo) ----
        float xv[8] = {xr0.x, xr0.y, xr0.z, xr0.w, xr1.x, xr1.y, xr1.z, xr1.w};
        FragU xhi, xlo;
        #pragma unroll
        for (int u = 0; u < 4; ++u)
            split2(xv[2 * u], xv[2 * u + 1], xhi.u[u], xlo.u[u]);

        // prefetch next t
        if (t < TT - 1) {
            const float* p = xbase + (t + 1) * II + 8 * g;
            xr0 = *(const float4*)p;
            xr1 = (g < 3) ? *(const float4*)(p + 4) : make_float4(1.f, 0.f, 0.f, 0.f);
        }

        // ---- x-projection (+bias): Whi*xhi + Whi*xlo + Wlo*xhi ----
        f32x4 accv[4];
        #pragma unroll
        for (int jt = 0; jt < 4; ++jt) {
            f32x4 a = {0.f, 0.f, 0.f, 0.f};
            a = MFMA(wihhi[jt].v, xhi.v, a);
            a = MFMA(wihhi[jt].v, xlo.v, a);
            a = MFMA(wihlo[jt].v, xhi.v, a);
            accv[jt] = a;
        }
        // ---- recurrent part ----
        if (t > 0) {
            #pragma unroll
            for (int jt = 0; jt < 4; ++jt) {
                f32x4 a = accv[jt];
                #pragma unroll
                for (int kb = 0; kb < 2; ++kb) {
                    a = MFMA(whhhi[jt][kb].v, hhi[kb].v, a);
                    a = MFMA(whhhi[jt][kb].v, hlo[kb].v, a);
                    a = MFMA(whhlo[jt][kb].v, hhi[kb].v, a);
                }
                accv[jt] = a;
            }
        }

        // ---- tanh(a) = 1 - 2/(1+exp(2a)) ----
        #pragma unroll
        for (int jt = 0; jt < 4; ++jt) {
            #pragma unroll
            for (int r = 0; r < 4; ++r) {
                float aa = accv[jt][r];
                float e = __expf(2.f * aa);
                th[jt][r] = 1.f - 2.f * __builtin_amdgcn_rcpf(e + 1.f);
            }
        }

        // ---- build next-step h B-fragments: purely lane-local ----
        if (t < TT - 1) {
            unsigned thh[4][2], thl[4][2];
            #pragma unroll
            for (int jt = 0; jt < 4; ++jt)
                #pragma unroll
                for (int u = 0; u < 2; ++u)
                    split2(th[jt][2 * u], th[jt][2 * u + 1],
                           thh[jt][u], thl[jt][u]);
            #pragma unroll
            for (int kb = 0; kb < 2; ++kb) {
                hhi[kb].u[0] = thh[2 * kb][0];
                hhi[kb].u[1] = thh[2 * kb][1];
                hhi[kb].u[2] = thh[2 * kb + 1][0];
                hhi[kb].u[3] = thh[2 * kb + 1][1];
                hlo[kb].u[0] = thl[2 * kb][0];
                hlo[kb].u[1] = thl[2 * kb][1];
                hlo[kb].u[2] = thl[2 * kb + 1][0];
                hlo[kb].u[3] = thl[2 * kb + 1][1];
            }
        }
    }

    // ---- output head: out[b,o] = h . W_out[o,:] + b_out[o] (permuted j) ----
    float po[OO];
    #pragma unroll
    for (int o = 0; o < OO; ++o) {
        float s = 0.f;
        #pragma unroll
        for (int jt = 0; jt < 4; ++jt) {
            const float* wp = W_out + o * HH + 32 * (jt >> 1) + 8 * g + 4 * (jt & 1);
            float4 wv = *(const float4*)wp;
            s += th[jt][0] * wv.x + th[jt][1] * wv.y +
                 th[jt][2] * wv.z + th[jt][3] * wv.w;
        }
        s += __shfl_xor(s, 16);
        s += __shfl_xor(s, 32);
        po[o] = s;
    }
    if (g == 0) {
        #pragma unroll
        for (int o = 0; o < OO; ++o)
            out[(size_t)bglob * OO + o] = po[o] + b_out[o];
    }
}

extern "C" void kernel_launch(void* const* d_in, const int* in_sizes, int n_in,
                              void* d_out, int out_size, void* d_ws, size_t ws_size,
                              hipStream_t stream) {
    const float* X     = (const float*)d_in[0];
    const float* W_ih  = (const float*)d_in[1];
    const float* W_hh  = (const float*)d_in[2];
    const float* b_ih  = (const float*)d_in[3];
    const float* b_hh  = (const float*)d_in[4];
    const float* W_out = (const float*)d_in[5];
    const float* b_out = (const float*)d_in[6];
    float* out = (float*)d_out;

    const int B = in_sizes[0] / (TT * II);   // 32768
    dim3 grid(B / 64), block(256);           // 4 waves x 16 batch elems per block
    hipLaunchKernelGGL(rnn_mfma2, grid, block, 0, stream,
                       X, W_ih, W_hh, b_ih, b_hh, W_out, b_out, out);
}

// Round 8
// 52.974 us; speedup vs baseline: 5.4956x; 1.0007x over previous
//
#include <hip/hip_runtime.h>

#define TT 28
#define II 28
#define HH 64
#define OO 10

typedef __attribute__((ext_vector_type(8))) __bf16 bf16x8;
typedef __attribute__((ext_vector_type(2))) __bf16 bf16x2;
typedef __attribute__((ext_vector_type(4))) float f32x4;

union FragU { unsigned u[4]; bf16x8 v; };

__device__ __forceinline__ unsigned cvtpk(float f0, float f1) {
    bf16x2 p; p.x = (__bf16)f0; p.y = (__bf16)f1;   // -> v_cvt_pk_bf16_f32
    return __builtin_bit_cast(unsigned, p);
}
// split (f0,f1) into packed bf16 hi + packed bf16 lo (residual)
__device__ __forceinline__ void split2(float f0, float f1, unsigned& hi, unsigned& lo) {
    unsigned hb = cvtpk(f0, f1);
    float h0 = __builtin_bit_cast(float, hb << 16);
    float h1 = __builtin_bit_cast(float, hb & 0xFFFF0000u);
    lo = cvtpk(f0 - h0, f1 - h1);
    hi = hb;
}

#define MFMA(A, B, C) __builtin_amdgcn_mfma_f32_16x16x32_bf16((A), (B), (C), 0, 0, 0)

// Transposed-recurrence MFMA RNN with PERMUTED row layout:
// A-frag tile jt carries W rows j(jt,rho) = 32*(jt>>1) + 8*(rho>>2) + 4*(jt&1) + (rho&3).
// Then lane (g,b) ends the step holding th[jt][r] = h[32*(jt>>1)+8g+4*(jt&1)+r],
// which is EXACTLY its own B-fragment for the next step:
//   Bfrag[kb][e] = th[2kb+(e>>2)][e&3]   (zero cross-lane traffic, zero LDS).
__global__ __launch_bounds__(256, 2) void rnn_mfma2(
    const float* __restrict__ X, const float* __restrict__ W_ih,
    const float* __restrict__ W_hh, const float* __restrict__ b_ih,
    const float* __restrict__ b_hh, const float* __restrict__ W_out,
    const float* __restrict__ b_out, float* __restrict__ out)
{
    const int lane = threadIdx.x & 63;
    const int wave = threadIdx.x >> 6;
    const int m15  = lane & 15;        // batch col for B/C, row-within-tile for A
    const int g    = lane >> 4;        // k-group / C row-group
    const int bglob = blockIdx.x * 64 + wave * 16 + m15;
    const int rowhi = 8 * (m15 >> 2) + (m15 & 3);   // permuted-row component

    // ---- W_hh A-fragments (hi/lo split), permuted rows ----
    FragU whhhi[4][2], whhlo[4][2];
    #pragma unroll
    for (int jt = 0; jt < 4; ++jt) {
        const int jA = 32 * (jt >> 1) + 4 * (jt & 1) + rowhi;
        #pragma unroll
        for (int kb = 0; kb < 2; ++kb) {
            const float* p = W_hh + jA * HH + 32 * kb + 8 * g;
            float4 a = *(const float4*)p;
            float4 c = *(const float4*)(p + 4);
            float w[8] = {a.x, a.y, a.z, a.w, c.x, c.y, c.z, c.w};
            #pragma unroll
            for (int u = 0; u < 4; ++u)
                split2(w[2 * u], w[2 * u + 1],
                       whhhi[jt][kb].u[u], whhlo[jt][kb].u[u]);
        }
    }

    // ---- W_ih A-fragments, K padded to 32 (k=28 carries bias), permuted rows ----
    FragU wihhi[4], wihlo[4];
    #pragma unroll
    for (int jt = 0; jt < 4; ++jt) {
        const int jA = 32 * (jt >> 1) + 4 * (jt & 1) + rowhi;
        float wv[8];
        #pragma unroll
        for (int e = 0; e < 8; ++e) {
            int k = 8 * g + e;
            float v = 0.f;
            if (k < II)       v = W_ih[jA * II + k];
            else if (k == II) v = b_ih[jA] + b_hh[jA];
            wv[e] = v;
        }
        #pragma unroll
        for (int u = 0; u < 4; ++u)
            split2(wv[2 * u], wv[2 * u + 1], wihhi[jt].u[u], wihlo[jt].u[u]);
    }

    const float* xbase = X + (size_t)bglob * (TT * II);

    // prefetch x for t=0 (k=28 is the bias column: x28 = 1)
    float4 xr0, xr1;
    {
        const float* p = xbase + 8 * g;
        xr0 = *(const float4*)p;
        xr1 = (g < 3) ? *(const float4*)(p + 4) : make_float4(1.f, 0.f, 0.f, 0.f);
    }

    FragU hhi[2], hlo[2];   // h B-fragments, valid for t>=1
    float th[4][4];

    for (int t = 0; t < TT; ++t) {
        // ---- build x B-fragments (hi/lo) ----
        float xv[8] = {xr0.x, xr0.y, xr0.z, xr0.w, xr1.x, xr1.y, xr1.z, xr1.w};
        FragU xhi, xlo;
        #pragma unroll
        for (int u = 0; u < 4; ++u)
            split2(xv[2 * u], xv[2 * u + 1], xhi.u[u], xlo.u[u]);

        // prefetch next t
        if (t < TT - 1) {
            const float* p = xbase + (t + 1) * II + 8 * g;
            xr0 = *(const float4*)p;
            xr1 = (g < 3) ? *(const float4*)(p + 4) : make_float4(1.f, 0.f, 0.f, 0.f);
        }

        // ---- x-projection (+bias): Whi*xhi + Whi*xlo + Wlo*xhi ----
        f32x4 accv[4];
        #pragma unroll
        for (int jt = 0; jt < 4; ++jt) {
            f32x4 a = {0.f, 0.f, 0.f, 0.f};
            a = MFMA(wihhi[jt].v, xhi.v, a);
            a = MFMA(wihhi[jt].v, xlo.v, a);
            a = MFMA(wihlo[jt].v, xhi.v, a);
            accv[jt] = a;
        }
        // ---- recurrent part ----
        if (t > 0) {
            #pragma unroll
            for (int jt = 0; jt < 4; ++jt) {
                f32x4 a = accv[jt];
                #pragma unroll
                for (int kb = 0; kb < 2; ++kb) {
                    a = MFMA(whhhi[jt][kb].v, hhi[kb].v, a);
                    a = MFMA(whhhi[jt][kb].v, hlo[kb].v, a);
                    a = MFMA(whhlo[jt][kb].v, hhi[kb].v, a);
                }
                accv[jt] = a;
            }
        }

        // ---- tanh(a) = 1 - 2/(1+exp(2a)) ----
        #pragma unroll
        for (int jt = 0; jt < 4; ++jt) {
            #pragma unroll
            for (int r = 0; r < 4; ++r) {
                float aa = accv[jt][r];
                float e = __expf(2.f * aa);
                th[jt][r] = 1.f - 2.f * __builtin_amdgcn_rcpf(e + 1.f);
            }
        }

        // ---- build next-step h B-fragments: purely lane-local ----
        if (t < TT - 1) {
            unsigned thh[4][2], thl[4][2];
            #pragma unroll
            for (int jt = 0; jt < 4; ++jt)
                #pragma unroll
                for (int u = 0; u < 2; ++u)
                    split2(th[jt][2 * u], th[jt][2 * u + 1],
                           thh[jt][u], thl[jt][u]);
            #pragma unroll
            for (int kb = 0; kb < 2; ++kb) {
                hhi[kb].u[0] = thh[2 * kb][0];
                hhi[kb].u[1] = thh[2 * kb][1];
                hhi[kb].u[2] = thh[2 * kb + 1][0];
                hhi[kb].u[3] = thh[2 * kb + 1][1];
                hlo[kb].u[0] = thl[2 * kb][0];
                hlo[kb].u[1] = thl[2 * kb][1];
                hlo[kb].u[2] = thl[2 * kb + 1][0];
                hlo[kb].u[3] = thl[2 * kb + 1][1];
            }
        }
    }

    // ---- output head: out[b,o] = h . W_out[o,:] + b_out[o] (permuted j) ----
    float po[OO];
    #pragma unroll
    for (int o = 0; o < OO; ++o) {
        float s = 0.f;
        #pragma unroll
        for (int jt = 0; jt < 4; ++jt) {
            const float* wp = W_out + o * HH + 32 * (jt >> 1) + 8 * g + 4 * (jt & 1);
            float4 wv = *(const float4*)wp;
            s += th[jt][0] * wv.x + th[jt][1] * wv.y +
                 th[jt][2] * wv.z + th[jt][3] * wv.w;
        }
        s += __shfl_xor(s, 16);
        s += __shfl_xor(s, 32);
        po[o] = s;
    }
    if (g == 0) {
        #pragma unroll
        for (int o = 0; o < OO; ++o)
            out[(size_t)bglob * OO + o] = po[o] + b_out[o];
    }
}

extern "C" void kernel_launch(void* const* d_in, const int* in_sizes, int n_in,
                              void* d_out, int out_size, void* d_ws, size_t ws_size,
                              hipStream_t stream) {
    const float* X     = (const float*)d_in[0];
    const float* W_ih  = (const float*)d_in[1];
    const float* W_hh  = (const float*)d_in[2];
    const float* b_ih  = (const float*)d_in[3];
    const float* b_hh  = (const float*)d_in[4];
    const float* W_out = (const float*)d_in[5];
    const float* b_out = (const float*)d_in[6];
    float* out = (float*)d_out;

    const int B = in_sizes[0] / (TT * II);   // 32768
    dim3 grid(B / 64), block(256);           // 4 waves x 16 batch elems per block
    hipLaunchKernelGGL(rnn_mfma2, grid, block, 0, stream,
                       X, W_ih, W_hh, b_ih, b_hh, W_out, b_out, out);
}